// Round 1
// baseline (882.873 us; speedup 1.0000x reference)
//
#include <hip/hip_runtime.h>
#include <stdint.h>

// Problem constants (fixed instance from setup_inputs)
#define B_   2
#define T_   64
#define S_   1024
#define C_   512
#define H_   8
#define HD_  64
#define N_   (T_ * S_)      // 65536
#define M_   (B_ * N_)      // 131072
#define WIN_ 5

typedef unsigned short u16;
typedef __bf16 bf16;
typedef __bf16 bf16x8 __attribute__((ext_vector_type(8)));
typedef float  f32x4  __attribute__((ext_vector_type(4)));
typedef u16    u16x8  __attribute__((ext_vector_type(8)));
typedef u16    u16x4  __attribute__((ext_vector_type(4)));
typedef float  f32x4g __attribute__((ext_vector_type(4)));

static __device__ inline u16 f2bf(float f) {
    bf16 h = (bf16)f;                       // RNE convert
    return __builtin_bit_cast(u16, h);
}
static __device__ inline float bf2f(u16 u) {
    return __builtin_bit_cast(float, (uint32_t)u << 16);
}

// ---------------------------------------------------------------------------
// GEMM: D[M x NCOL] = A[M x 512] * B[512 x NCOL]
// A is fp32 or bf16 (A_BF16), B is fp32, D is bf16 or fp32 (OUT_BF16).
// 128x128 tile, BK=32, 4 waves (2x2 of 64x64), mfma_f32_16x16x32_bf16.
// LDS tiles stored [row][k] (A) and [n][k ^ swz(n)] (B, transposed on store).
// ---------------------------------------------------------------------------
template<int NCOL, bool A_BF16, bool OUT_BF16>
__global__ __launch_bounds__(256) void gemm_k(const void* __restrict__ Ap,
                                              const float* __restrict__ Bp,
                                              void* __restrict__ Dp) {
    constexpr int K = 512;
    __shared__ u16 As[128][40];   // row stride 80B (16B-aligned), +8 pad
    __shared__ u16 Bs[128][40];   // [n][k'], k' = k ^ swz(n)

    const int tid  = threadIdx.x;
    const int lane = tid & 63;
    const int wid  = tid >> 6;
    const int wr   = wid >> 1;    // wave row (0..1)
    const int wc   = wid & 1;     // wave col (0..1)
    const long row0 = (long)blockIdx.y * 128;
    const int  col0 = blockIdx.x * 128;

    f32x4 acc[4][4] = {};

    const int arow = tid >> 1;          // 0..127
    const int akof = (tid & 1) << 4;    // 0 or 16
    const int bkr  = tid >> 3;          // 0..31
    const int bnof = (tid & 7) << 4;    // 0..112

    for (int kt = 0; kt < K / 32; ++kt) {
        const int k0 = kt * 32;
        __syncthreads();
        // ---- stage A tile (128 x 32) ----
        if (!A_BF16) {
            const float* src = (const float*)Ap + (row0 + arow) * (long)K + k0 + akof;
            #pragma unroll
            for (int i = 0; i < 4; ++i) {
                f32x4g v = *(const f32x4g*)(src + i * 4);
                u16x4 w;
                #pragma unroll
                for (int j = 0; j < 4; ++j) w[j] = f2bf(v[j]);
                *(u16x4*)&As[arow][akof + i * 4] = w;
            }
        } else {
            const u16* src = (const u16*)Ap + (row0 + arow) * (long)K + k0 + akof;
            *(u16x8*)&As[arow][akof]     = *(const u16x8*)src;
            *(u16x8*)&As[arow][akof + 8] = *(const u16x8*)(src + 8);
        }
        // ---- stage B tile (32 x 128), transposed into [n][k'] ----
        {
            const float* src = Bp + (long)(k0 + bkr) * NCOL + col0 + bnof;
            #pragma unroll
            for (int i = 0; i < 16; ++i) {
                float v = src[i];
                int n  = bnof + i;
                int kk = bkr ^ ((((n >> 4) ^ n) & 3) << 3);
                Bs[n][kk] = f2bf(v);
            }
        }
        __syncthreads();
        // ---- fragments + 16 MFMAs ----
        bf16x8 af[4], bfr[4];
        #pragma unroll
        for (int mf = 0; mf < 4; ++mf) {
            int r = wr * 64 + mf * 16 + (lane & 15);
            u16x8 raw = *(const u16x8*)&As[r][(lane >> 4) * 8];
            af[mf] = __builtin_bit_cast(bf16x8, raw);
        }
        #pragma unroll
        for (int nf = 0; nf < 4; ++nf) {
            int n   = wc * 64 + nf * 16 + (lane & 15);
            int kof = ((lane >> 4) * 8) ^ ((((n >> 4) ^ n) & 3) << 3);
            u16x8 raw = *(const u16x8*)&Bs[n][kof];
            bfr[nf] = __builtin_bit_cast(bf16x8, raw);
        }
        #pragma unroll
        for (int mf = 0; mf < 4; ++mf)
            #pragma unroll
            for (int nf = 0; nf < 4; ++nf)
                acc[mf][nf] = __builtin_amdgcn_mfma_f32_16x16x32_bf16(
                    af[mf], bfr[nf], acc[mf][nf], 0, 0, 0);
    }
    // ---- epilogue: D row = (lane>>4)*4 + r, col = lane&15 ----
    #pragma unroll
    for (int mf = 0; mf < 4; ++mf) {
        #pragma unroll
        for (int nf = 0; nf < 4; ++nf) {
            #pragma unroll
            for (int r = 0; r < 4; ++r) {
                long grow = row0 + wr * 64 + mf * 16 + (lane >> 4) * 4 + r;
                int  gcol = col0 + wc * 64 + nf * 16 + (lane & 15);
                float v = acc[mf][nf][r];
                if (OUT_BF16) ((u16*)Dp)[grow * NCOL + gcol] = f2bf(v);
                else          ((float*)Dp)[grow * NCOL + gcol] = v;
            }
        }
    }
}

// ---------------------------------------------------------------------------
// Banded temporal attention. One wave per (b, h, s). qkv layout:
// qkv[((b*T + t)*S + s)*1536 + which*512 + h*64 + d], bf16 bits in u16.
// Thread t owns output row t: dot over hd=64 for u in [t-5, t+5].
// ---------------------------------------------------------------------------
__global__ __launch_bounds__(64) void attn_k(const u16* __restrict__ qkv,
                                             u16* __restrict__ attn) {
    __shared__ u16 Kl[64][72];   // row stride 144B (16B-aligned)
    __shared__ u16 Vl[64][72];

    const int tid = threadIdx.x;
    const int bid = blockIdx.x;
    const int s = bid & (S_ - 1);
    const int h = (bid >> 10) & (H_ - 1);
    const int b = bid >> 13;

    const size_t base = ((size_t)b * T_ * S_ + s) * 1536 + h * 64;

    // stage K, V rows cooperatively (8 rows x 8 chunks per pass)
    {
        const int rr = tid >> 3;
        const int ch = tid & 7;
        #pragma unroll
        for (int it = 0; it < 8; ++it) {
            int tt = it * 8 + rr;
            size_t off = base + (size_t)tt * (S_ * 1536) + ch * 8;
            *(u16x8*)&Kl[tt][ch * 8] = *(const u16x8*)(qkv + off + 512);
            *(u16x8*)&Vl[tt][ch * 8] = *(const u16x8*)(qkv + off + 1024);
        }
    }
    // Q row into registers (fp32)
    float qf[64];
    const int t = tid;
    {
        size_t qoff = base + (size_t)t * (S_ * 1536);
        #pragma unroll
        for (int c = 0; c < 8; ++c) {
            u16x8 v = *(const u16x8*)(qkv + qoff + c * 8);
            #pragma unroll
            for (int j = 0; j < 8; ++j) qf[c * 8 + j] = bf2f(v[j]);
        }
    }
    __syncthreads();

    // scores over the band, softmax
    float p[11];
    float m = -1e30f;
    #pragma unroll
    for (int i = 0; i < 11; ++i) {
        int u = t - WIN_ + i;
        if (u >= 0 && u < 64) {
            float dot = 0.f;
            #pragma unroll
            for (int c = 0; c < 8; ++c) {
                u16x8 kv = *(const u16x8*)&Kl[u][c * 8];
                #pragma unroll
                for (int j = 0; j < 8; ++j) dot += qf[c * 8 + j] * bf2f(kv[j]);
            }
            p[i] = dot * 0.125f;   // hd^-0.5
            m = fmaxf(m, p[i]);
        } else {
            p[i] = -1e30f;
        }
    }
    float sum = 0.f;
    #pragma unroll
    for (int i = 0; i < 11; ++i) {
        int u = t - WIN_ + i;
        float e = (u >= 0 && u < 64) ? __expf(p[i] - m) : 0.f;
        p[i] = e;
        sum += e;
    }
    const float inv = 1.f / sum;

    // PV
    float o[64];
    #pragma unroll
    for (int d = 0; d < 64; ++d) o[d] = 0.f;
    #pragma unroll
    for (int i = 0; i < 11; ++i) {
        int u = t - WIN_ + i;
        if (u >= 0 && u < 64) {
            float pv = p[i] * inv;
            #pragma unroll
            for (int c = 0; c < 8; ++c) {
                u16x8 vv = *(const u16x8*)&Vl[u][c * 8];
                #pragma unroll
                for (int j = 0; j < 8; ++j) o[c * 8 + j] += pv * bf2f(vv[j]);
            }
        }
    }
    // store attn row (bf16)
    size_t ooff = (((size_t)b * T_ + t) * S_ + s) * (size_t)C_ + h * 64;
    #pragma unroll
    for (int c = 0; c < 8; ++c) {
        u16x8 w;
        #pragma unroll
        for (int j = 0; j < 8; ++j) w[j] = f2bf(o[c * 8 + j]);
        *(u16x8*)&attn[ooff + c * 8] = w;
    }
}

// ---------------------------------------------------------------------------
extern "C" void kernel_launch(void* const* d_in, const int* in_sizes, int n_in,
                              void* d_out, int out_size, void* d_ws, size_t ws_size,
                              hipStream_t stream) {
    const float* x    = (const float*)d_in[0];   // (B, N, C) fp32
    const float* Wqkv = (const float*)d_in[1];   // (C, 3C) fp32
    const float* Wout = (const float*)d_in[2];   // (C, C) fp32
    float* out = (float*)d_out;                  // (B, N, C) fp32

    // workspace: qkv bf16 (M x 1536) then attn bf16 (M x 512)
    const size_t qkv_elems = (size_t)M_ * 1536;
    const size_t attn_elems = (size_t)M_ * C_;
    if (ws_size < (qkv_elems + attn_elems) * sizeof(u16)) return; // need 512 MiB
    u16* qkv  = (u16*)d_ws;
    u16* attn = qkv + qkv_elems;

    // 1) qkv = x @ W_qkv   (fp32 in, bf16 out)
    gemm_k<1536, false, true><<<dim3(1536 / 128, M_ / 128), 256, 0, stream>>>(
        (const void*)x, Wqkv, (void*)qkv);

    // 2) banded temporal attention
    attn_k<<<B_ * H_ * S_, 64, 0, stream>>>(qkv, attn);

    // 3) out = attn @ W_out  (bf16 in, fp32 out)
    gemm_k<512, true, false><<<dim3(512 / 128, M_ / 128), 256, 0, stream>>>(
        (const void*)attn, Wout, (void*)out);
}

// Round 2
// 774.117 us; speedup vs baseline: 1.1405x; 1.1405x over previous
//
#include <hip/hip_runtime.h>
#include <stdint.h>

// Problem constants (fixed instance from setup_inputs)
#define B_   2
#define T_   64
#define S_   1024
#define C_   512
#define H_   8
#define N_   (T_ * S_)      // 65536
#define M_   (B_ * N_)      // 131072
#define WIN_ 5

typedef unsigned short u16;
typedef __bf16 bf16;
typedef __bf16 bf16x8 __attribute__((ext_vector_type(8)));
typedef float  f32x4  __attribute__((ext_vector_type(4)));
typedef u16    u16x8  __attribute__((ext_vector_type(8)));

static __device__ __forceinline__ u16 f2bf(float f) {
    return __builtin_bit_cast(u16, (bf16)f);   // RNE
}
static __device__ __forceinline__ float bf2f(u16 u) {
    return __builtin_bit_cast(float, (uint32_t)u << 16);
}
// async global->LDS, 16B per lane; LDS dest is wave-uniform base + lane*16
static __device__ __forceinline__ void gload16(const void* g, void* l) {
    __builtin_amdgcn_global_load_lds(
        (const __attribute__((address_space(1))) void*)g,
        (__attribute__((address_space(3))) void*)l, 16, 0, 0);
}

// ---------------------------------------------------------------------------
// Weight prep: W [512][NCOL] fp32  ->  WT [NCOL][512] bf16, pre-swizzled.
// Swizzle: within each 64B chunk (4 granules of 16B), logical granule g is
// stored at g ^ ((row>>1)&3)  (row = n mod 128). Self-inverse XOR.
// ---------------------------------------------------------------------------
__global__ __launch_bounds__(256) void prep_w(const float* __restrict__ W,
                                              u16* __restrict__ WT, int NCOL) {
    int id = blockIdx.x * 256 + threadIdx.x;
    int n  = id % NCOL;            // consecutive threads -> consecutive n (coalesced reads)
    int gi = id / NCOL;            // 0..63: granule index within the 512-elem row
    int chunk = gi >> 2;           // 16 chunks of 32 elems
    int g     = gi & 3;
    int k0 = chunk * 32 + g * 8;
    int gs = g ^ ((n >> 1) & 3);
    u16x8 w;
    #pragma unroll
    for (int j = 0; j < 8; ++j) w[j] = f2bf(W[(size_t)(k0 + j) * NCOL + n]);
    *(u16x8*)&WT[(size_t)n * 512 + chunk * 32 + gs * 8] = w;
}

// ---------------------------------------------------------------------------
// GEMM: D[M x NCOL] = A[M x 512] * B[512 x NCOL], m97 structure.
// B is pre-transposed/pre-swizzled bf16 [NCOL][512] -> global_load_lds.
// A_F32: A fp32 row-major, reg-staged with convert + swizzled ds_write_b128,
//        next-tile global loads prefetched under the MFMAs.
// else:  A pre-swizzled bf16 [M][512] -> global_load_lds.
// 128x128 tile, BK=32, 4 waves (2x2 of 64x64), mfma_f32_16x16x32_bf16.
// LDS [row][32] bf16 linear (64B rows), granule-XOR swizzle on frag reads.
// ---------------------------------------------------------------------------
template<int NCOL, bool A_F32, bool OUT_BF16>
__global__ __launch_bounds__(256) void gemm_k(const void* __restrict__ Ap,
                                              const u16* __restrict__ Bp,
                                              void* __restrict__ Dp, int gx) {
    __shared__ u16 As[128 * 32];   // 8 KiB
    __shared__ u16 Bs[128 * 32];   // 8 KiB

    const int tid  = threadIdx.x;
    const int lane = tid & 63;
    const int wid  = tid >> 6;
    const int wr   = wid >> 1;
    const int wc   = wid & 1;

    // XCD-aware bijective swizzle (gridDim.x % 8 == 0 for both instantiations)
    const int nwg = gridDim.x;
    const int q8  = nwg >> 3;
    const int bid = blockIdx.x;
    const int wg  = (bid & 7) * q8 + (bid >> 3);
    const int bx  = wg % gx;
    const int by  = wg / gx;
    const long row0 = (long)by * 128;
    const int  col0 = bx * 128;

    // frag read offsets (u16 units), swizzled
    int aoff[4], boff[4];
    #pragma unroll
    for (int f = 0; f < 4; ++f) {
        int ra = wr * 64 + f * 16 + (lane & 15);
        aoff[f] = ra * 32 + ((((lane >> 4) ^ (ra >> 1)) & 3) << 3);
        int rb = wc * 64 + f * 16 + (lane & 15);
        boff[f] = rb * 32 + ((((lane >> 4) ^ (rb >> 1)) & 3) << 3);
    }

    // A staging (reg-staged fp32 path)
    const int arow = tid >> 1;          // 0..127
    const int akh  = tid & 1;           // which 16-elem half of the 32-k window
    int aw0 = 0, aw1 = 0;
    const float* asrc = nullptr;
    if constexpr (A_F32) {
        int key = (arow >> 1) & 3;
        aw0 = arow * 32 + (((akh * 2 + 0) ^ key) << 3);
        aw1 = arow * 32 + (((akh * 2 + 1) ^ key) << 3);
        asrc = (const float*)Ap + (row0 + arow) * 512 + akh * 16;
    }

    f32x4 acc[4][4] = {};
    f32x4 areg[4];
    if constexpr (A_F32) {
        #pragma unroll
        for (int i = 0; i < 4; ++i) areg[i] = *(const f32x4*)(asrc + i * 4);
    }

    for (int kt = 0; kt < 16; ++kt) {
        const int k0 = kt * 32;
        __syncthreads();
        // ---- stage A ----
        if constexpr (A_F32) {
            u16x8 w0, w1;
            #pragma unroll
            for (int j = 0; j < 4; ++j) {
                w0[j] = f2bf(areg[0][j]); w0[4 + j] = f2bf(areg[1][j]);
                w1[j] = f2bf(areg[2][j]); w1[4 + j] = f2bf(areg[3][j]);
            }
            *(u16x8*)&As[aw0] = w0;
            *(u16x8*)&As[aw1] = w1;
        } else {
            const u16* Abf = (const u16*)Ap;
            #pragma unroll
            for (int j = 0; j < 2; ++j) {
                const u16* g = Abf + (row0 + wid * 32 + j * 16 + (lane >> 2)) * 512
                                   + k0 + (lane & 3) * 8;
                gload16(g, (void*)&As[(wid * 2 + j) * 512]);
            }
        }
        // ---- stage B ----
        #pragma unroll
        for (int j = 0; j < 2; ++j) {
            const u16* g = Bp + (size_t)(col0 + wid * 32 + j * 16 + (lane >> 2)) * 512
                              + k0 + (lane & 3) * 8;
            gload16(g, (void*)&Bs[(wid * 2 + j) * 512]);
        }
        __syncthreads();
        // ---- prefetch next A tile (hides under MFMAs) ----
        if constexpr (A_F32) {
            if (kt < 15) {
                #pragma unroll
                for (int i = 0; i < 4; ++i)
                    areg[i] = *(const f32x4*)(asrc + (kt + 1) * 32 + i * 4);
            }
        }
        // ---- fragments + 16 MFMAs ----
        bf16x8 af[4], bfr[4];
        #pragma unroll
        for (int f = 0; f < 4; ++f) af[f]  = __builtin_bit_cast(bf16x8, *(const u16x8*)&As[aoff[f]]);
        #pragma unroll
        for (int f = 0; f < 4; ++f) bfr[f] = __builtin_bit_cast(bf16x8, *(const u16x8*)&Bs[boff[f]]);
        #pragma unroll
        for (int mf = 0; mf < 4; ++mf)
            #pragma unroll
            for (int nf = 0; nf < 4; ++nf)
                acc[mf][nf] = __builtin_amdgcn_mfma_f32_16x16x32_bf16(
                    af[mf], bfr[nf], acc[mf][nf], 0, 0, 0);
    }
    // ---- epilogue: row = (lane>>4)*4 + r, col = lane&15 ----
    #pragma unroll
    for (int mf = 0; mf < 4; ++mf) {
        #pragma unroll
        for (int nf = 0; nf < 4; ++nf) {
            #pragma unroll
            for (int r = 0; r < 4; ++r) {
                long grow = row0 + wr * 64 + mf * 16 + (lane >> 4) * 4 + r;
                int  gcol = col0 + wc * 64 + nf * 16 + (lane & 15);
                float v = acc[mf][nf][r];
                if constexpr (OUT_BF16) ((u16*)Dp)[grow * NCOL + gcol] = f2bf(v);
                else                    ((float*)Dp)[grow * NCOL + gcol] = v;
            }
        }
    }
}

// ---------------------------------------------------------------------------
// Banded temporal attention. One wave per (b, h, s). qkv layout (linear bf16):
// qkv[((b*T + t)*S + s)*1536 + which*512 + h*64 + d].
// Output rows are stored PRE-SWIZZLED for gemm3's global_load_lds staging.
// ---------------------------------------------------------------------------
__global__ __launch_bounds__(64) void attn_k(const u16* __restrict__ qkv,
                                             u16* __restrict__ attn) {
    __shared__ u16 Kl[64][72];
    __shared__ u16 Vl[64][72];

    const int tid = threadIdx.x;
    const int bid = blockIdx.x;
    const int s = bid & (S_ - 1);
    const int h = (bid >> 10) & (H_ - 1);
    const int b = bid >> 13;

    const size_t base = ((size_t)b * T_ * S_ + s) * 1536 + h * 64;

    {
        const int rr = tid >> 3;
        const int ch = tid & 7;
        #pragma unroll
        for (int it = 0; it < 8; ++it) {
            int tt = it * 8 + rr;
            size_t off = base + (size_t)tt * (S_ * 1536) + ch * 8;
            *(u16x8*)&Kl[tt][ch * 8] = *(const u16x8*)(qkv + off + 512);
            *(u16x8*)&Vl[tt][ch * 8] = *(const u16x8*)(qkv + off + 1024);
        }
    }
    float qf[64];
    const int t = tid;
    {
        size_t qoff = base + (size_t)t * (S_ * 1536);
        #pragma unroll
        for (int c = 0; c < 8; ++c) {
            u16x8 v = *(const u16x8*)(qkv + qoff + c * 8);
            #pragma unroll
            for (int j = 0; j < 8; ++j) qf[c * 8 + j] = bf2f(v[j]);
        }
    }
    __syncthreads();

    float p[11];
    float m = -1e30f;
    #pragma unroll
    for (int i = 0; i < 11; ++i) {
        int u = t - WIN_ + i;
        if (u >= 0 && u < 64) {
            float dot = 0.f;
            #pragma unroll
            for (int c = 0; c < 8; ++c) {
                u16x8 kv = *(const u16x8*)&Kl[u][c * 8];
                #pragma unroll
                for (int j = 0; j < 8; ++j) dot += qf[c * 8 + j] * bf2f(kv[j]);
            }
            p[i] = dot * 0.125f;
            m = fmaxf(m, p[i]);
        } else {
            p[i] = -1e30f;
        }
    }
    float sum = 0.f;
    #pragma unroll
    for (int i = 0; i < 11; ++i) {
        int u = t - WIN_ + i;
        float e = (u >= 0 && u < 64) ? __expf(p[i] - m) : 0.f;
        p[i] = e;
        sum += e;
    }
    const float inv = 1.f / sum;

    float o[64];
    #pragma unroll
    for (int d = 0; d < 64; ++d) o[d] = 0.f;
    #pragma unroll
    for (int i = 0; i < 11; ++i) {
        int u = t - WIN_ + i;
        if (u >= 0 && u < 64) {
            float pv = p[i] * inv;
            #pragma unroll
            for (int c = 0; c < 8; ++c) {
                u16x8 vv = *(const u16x8*)&Vl[u][c * 8];
                #pragma unroll
                for (int j = 0; j < 8; ++j) o[c * 8 + j] += pv * bf2f(vv[j]);
            }
        }
    }
    // store pre-swizzled: row r = s mod 128; granule (c&3) -> (c&3)^((r>>1)&3)
    size_t rowbase = (((size_t)b * T_ + t) * S_ + s) * (size_t)C_;
    const int key = (s >> 1) & 3;
    #pragma unroll
    for (int c = 0; c < 8; ++c) {
        u16x8 w;
        #pragma unroll
        for (int j = 0; j < 8; ++j) w[j] = f2bf(o[c * 8 + j]);
        int off = h * 64 + (c >> 2) * 32 + (((c & 3) ^ key) << 3);
        *(u16x8*)&attn[rowbase + off] = w;
    }
}

// ---------------------------------------------------------------------------
extern "C" void kernel_launch(void* const* d_in, const int* in_sizes, int n_in,
                              void* d_out, int out_size, void* d_ws, size_t ws_size,
                              hipStream_t stream) {
    const float* x    = (const float*)d_in[0];   // (B, N, C) fp32
    const float* Wqkv = (const float*)d_in[1];   // (512, 1536) fp32
    const float* Wout = (const float*)d_in[2];   // (512, 512) fp32
    float* out = (float*)d_out;

    const size_t attn_elems = (size_t)M_ * C_;      // 67.1M
    const size_t qkv_elems  = (size_t)M_ * 1536;    // 201.3M
    if (ws_size < (attn_elems + qkv_elems) * sizeof(u16)) return;

    u16* attn_buf = (u16*)d_ws;                 // [0, 134MB)
    u16* qkv      = attn_buf + attn_elems;      // [134MB, 537MB)
    u16* WqkvT    = attn_buf;                   // aliased: used before attn_buf written
    u16* WoutT    = qkv;                        // aliased: used after qkv dead

    // 1) WqkvT = preswizzled bf16 transpose of Wqkv (lives in attn_buf region)
    prep_w<<<(1536 * 64) / 256, 256, 0, stream>>>(Wqkv, WqkvT, 1536);

    // 2) qkv = x @ W_qkv  (fp32 A reg-staged, bf16 out, linear layout)
    gemm_k<1536, true, true><<<12288, 256, 0, stream>>>(
        (const void*)x, WqkvT, (void*)qkv, 12);

    // 3) banded temporal attention (reads qkv, writes attn_buf pre-swizzled)
    attn_k<<<B_ * H_ * S_, 64, 0, stream>>>(qkv, attn_buf);

    // 4) WoutT into the now-dead qkv region
    prep_w<<<(512 * 64) / 256, 256, 0, stream>>>(Wout, WoutT, 512);

    // 5) out = attn @ W_out  (bf16 gload_lds A, fp32 out)
    gemm_k<512, false, false><<<4096, 256, 0, stream>>>(
        (const void*)attn_buf, WoutT, (void*)out, 4);
}

// Round 3
// 738.830 us; speedup vs baseline: 1.1950x; 1.0478x over previous
//
#include <hip/hip_runtime.h>
#include <stdint.h>

// Problem constants (fixed instance from setup_inputs)
#define B_   2
#define T_   64
#define S_   1024
#define C_   512
#define H_   8
#define N_   (T_ * S_)      // 65536
#define M_   (B_ * N_)      // 131072
#define WIN_ 5

typedef unsigned short u16;
typedef __bf16 bf16;
typedef __bf16 bf16x8 __attribute__((ext_vector_type(8)));
typedef float  f32x4  __attribute__((ext_vector_type(4)));
typedef u16    u16x8  __attribute__((ext_vector_type(8)));

static __device__ __forceinline__ u16 f2bf(float f) {
    return __builtin_bit_cast(u16, (bf16)f);   // RNE
}
static __device__ __forceinline__ float bf2f(u16 u) {
    return __builtin_bit_cast(float, (uint32_t)u << 16);
}
// async global->LDS, 16B per lane; LDS dest is wave-uniform base + lane*16
static __device__ __forceinline__ void gload16(const void* g, void* l) {
    __builtin_amdgcn_global_load_lds(
        (const __attribute__((address_space(1))) void*)g,
        (__attribute__((address_space(3))) void*)l, 16, 0, 0);
}

// ---------------------------------------------------------------------------
// Weight prep: W [512][NCOL] fp32  ->  WT [NCOL][512] bf16, pre-swizzled.
// Swizzle: within each 64B chunk (4 granules of 16B), logical granule g is
// stored at g ^ ((row>>1)&3). Self-inverse XOR.
// ---------------------------------------------------------------------------
__global__ __launch_bounds__(256) void prep_w(const float* __restrict__ W,
                                              u16* __restrict__ WT, int NCOL) {
    int id = blockIdx.x * 256 + threadIdx.x;
    int n  = id % NCOL;            // consecutive threads -> consecutive n (coalesced reads)
    int gi = id / NCOL;            // 0..63: granule index within the 512-elem row
    int chunk = gi >> 2;           // 16 chunks of 32 elems
    int g     = gi & 3;
    int k0 = chunk * 32 + g * 8;
    int gs = g ^ ((n >> 1) & 3);
    u16x8 w;
    #pragma unroll
    for (int j = 0; j < 8; ++j) w[j] = f2bf(W[(size_t)(k0 + j) * NCOL + n]);
    *(u16x8*)&WT[(size_t)n * 512 + chunk * 32 + gs * 8] = w;
}

// ---------------------------------------------------------------------------
// x prep: x [M][512] fp32 -> xb [M][512] bf16, pre-swizzled (same granule XOR,
// key = (row>>1)&3). Fully coalesced: one wave reads a 2 KB contiguous row.
// ---------------------------------------------------------------------------
__global__ __launch_bounds__(256) void prep_x(const float* __restrict__ x,
                                              u16* __restrict__ xb) {
    const size_t total = (size_t)M_ * 64;   // 16B granules
    for (size_t id = (size_t)blockIdx.x * 256 + threadIdx.x; id < total;
         id += (size_t)gridDim.x * 256) {
        size_t r  = id >> 6;
        int   gi  = (int)(id & 63);
        int chunk = gi >> 2;
        int g     = gi & 3;
        int key   = ((int)r >> 1) & 3;
        const float* src = x + r * 512 + chunk * 32 + g * 8;
        u16x8 w;
        #pragma unroll
        for (int j = 0; j < 8; ++j) w[j] = f2bf(src[j]);
        *(u16x8*)&xb[r * 512 + chunk * 32 + ((g ^ key) << 3)] = w;
    }
}

// ---------------------------------------------------------------------------
// GEMM: D[M x NCOL] = A[M x 512] * B[512 x NCOL], m97 structure.
// A and B both pre-swizzled bf16 ([M][512] / [NCOL][512]) -> global_load_lds.
// 128x128 tile, BK=32, 4 waves (2x2 of 64x64), mfma_f32_16x16x32_bf16.
// LDS [row][32] bf16 linear (64B rows), granule-XOR swizzle on frag reads.
// ---------------------------------------------------------------------------
template<int NCOL, bool OUT_BF16>
__global__ __launch_bounds__(256) void gemm_k(const u16* __restrict__ Ap,
                                              const u16* __restrict__ Bp,
                                              void* __restrict__ Dp, int gx) {
    __shared__ u16 As[128 * 32];   // 8 KiB
    __shared__ u16 Bs[128 * 32];   // 8 KiB

    const int tid  = threadIdx.x;
    const int lane = tid & 63;
    const int wid  = tid >> 6;
    const int wr   = wid >> 1;
    const int wc   = wid & 1;

    // XCD-aware bijective swizzle (gridDim.x % 8 == 0 for both instantiations)
    const int nwg = gridDim.x;
    const int q8  = nwg >> 3;
    const int bid = blockIdx.x;
    const int wg  = (bid & 7) * q8 + (bid >> 3);
    const int bx  = wg % gx;
    const int by  = wg / gx;
    const long row0 = (long)by * 128;
    const int  col0 = bx * 128;

    // frag read offsets (u16 units), swizzled
    int aoff[4], boff[4];
    #pragma unroll
    for (int f = 0; f < 4; ++f) {
        int ra = wr * 64 + f * 16 + (lane & 15);
        aoff[f] = ra * 32 + ((((lane >> 4) ^ (ra >> 1)) & 3) << 3);
        int rb = wc * 64 + f * 16 + (lane & 15);
        boff[f] = rb * 32 + ((((lane >> 4) ^ (rb >> 1)) & 3) << 3);
    }

    f32x4 acc[4][4] = {};

    for (int kt = 0; kt < 16; ++kt) {
        const int k0 = kt * 32;
        __syncthreads();
        // ---- stage A (128 x 32 bf16) ----
        #pragma unroll
        for (int j = 0; j < 2; ++j) {
            const u16* g = Ap + (row0 + wid * 32 + j * 16 + (lane >> 2)) * 512
                              + k0 + (lane & 3) * 8;
            gload16(g, (void*)&As[(wid * 2 + j) * 512]);
        }
        // ---- stage B (128 x 32 bf16) ----
        #pragma unroll
        for (int j = 0; j < 2; ++j) {
            const u16* g = Bp + (size_t)(col0 + wid * 32 + j * 16 + (lane >> 2)) * 512
                              + k0 + (lane & 3) * 8;
            gload16(g, (void*)&Bs[(wid * 2 + j) * 512]);
        }
        __syncthreads();
        // ---- fragments + 16 MFMAs ----
        bf16x8 af[4], bfr[4];
        #pragma unroll
        for (int f = 0; f < 4; ++f) af[f]  = __builtin_bit_cast(bf16x8, *(const u16x8*)&As[aoff[f]]);
        #pragma unroll
        for (int f = 0; f < 4; ++f) bfr[f] = __builtin_bit_cast(bf16x8, *(const u16x8*)&Bs[boff[f]]);
        #pragma unroll
        for (int mf = 0; mf < 4; ++mf)
            #pragma unroll
            for (int nf = 0; nf < 4; ++nf)
                acc[mf][nf] = __builtin_amdgcn_mfma_f32_16x16x32_bf16(
                    af[mf], bfr[nf], acc[mf][nf], 0, 0, 0);
    }
    // ---- epilogue: row = (lane>>4)*4 + r, col = lane&15 ----
    #pragma unroll
    for (int mf = 0; mf < 4; ++mf) {
        #pragma unroll
        for (int nf = 0; nf < 4; ++nf) {
            #pragma unroll
            for (int r = 0; r < 4; ++r) {
                long grow = row0 + wr * 64 + mf * 16 + (lane >> 4) * 4 + r;
                int  gcol = col0 + wc * 64 + nf * 16 + (lane & 15);
                float v = acc[mf][nf][r];
                if constexpr (OUT_BF16) ((u16*)Dp)[grow * NCOL + gcol] = f2bf(v);
                else                    ((float*)Dp)[grow * NCOL + gcol] = v;
            }
        }
    }
}

// ---------------------------------------------------------------------------
// Banded temporal attention. One wave per (b, h, s). qkv layout (linear bf16):
// qkv[((b*T + t)*S + s)*1536 + which*512 + h*64 + d].
// Output rows are stored PRE-SWIZZLED for gemm3's global_load_lds staging.
// ---------------------------------------------------------------------------
__global__ __launch_bounds__(64) void attn_k(const u16* __restrict__ qkv,
                                             u16* __restrict__ attn) {
    __shared__ u16 Kl[64][72];
    __shared__ u16 Vl[64][72];

    const int tid = threadIdx.x;
    const int bid = blockIdx.x;
    const int s = bid & (S_ - 1);
    const int h = (bid >> 10) & (H_ - 1);
    const int b = bid >> 13;

    const size_t base = ((size_t)b * T_ * S_ + s) * 1536 + h * 64;

    {
        const int rr = tid >> 3;
        const int ch = tid & 7;
        #pragma unroll
        for (int it = 0; it < 8; ++it) {
            int tt = it * 8 + rr;
            size_t off = base + (size_t)tt * (S_ * 1536) + ch * 8;
            *(u16x8*)&Kl[tt][ch * 8] = *(const u16x8*)(qkv + off + 512);
            *(u16x8*)&Vl[tt][ch * 8] = *(const u16x8*)(qkv + off + 1024);
        }
    }
    float qf[64];
    const int t = tid;
    {
        size_t qoff = base + (size_t)t * (S_ * 1536);
        #pragma unroll
        for (int c = 0; c < 8; ++c) {
            u16x8 v = *(const u16x8*)(qkv + qoff + c * 8);
            #pragma unroll
            for (int j = 0; j < 8; ++j) qf[c * 8 + j] = bf2f(v[j]);
        }
    }
    __syncthreads();

    float p[11];
    float m = -1e30f;
    #pragma unroll
    for (int i = 0; i < 11; ++i) {
        int u = t - WIN_ + i;
        if (u >= 0 && u < 64) {
            float dot = 0.f;
            #pragma unroll
            for (int c = 0; c < 8; ++c) {
                u16x8 kv = *(const u16x8*)&Kl[u][c * 8];
                #pragma unroll
                for (int j = 0; j < 8; ++j) dot += qf[c * 8 + j] * bf2f(kv[j]);
            }
            p[i] = dot * 0.125f;
            m = fmaxf(m, p[i]);
        } else {
            p[i] = -1e30f;
        }
    }
    float sum = 0.f;
    #pragma unroll
    for (int i = 0; i < 11; ++i) {
        int u = t - WIN_ + i;
        float e = (u >= 0 && u < 64) ? __expf(p[i] - m) : 0.f;
        p[i] = e;
        sum += e;
    }
    const float inv = 1.f / sum;

    float o[64];
    #pragma unroll
    for (int d = 0; d < 64; ++d) o[d] = 0.f;
    #pragma unroll
    for (int i = 0; i < 11; ++i) {
        int u = t - WIN_ + i;
        if (u >= 0 && u < 64) {
            float pv = p[i] * inv;
            #pragma unroll
            for (int c = 0; c < 8; ++c) {
                u16x8 vv = *(const u16x8*)&Vl[u][c * 8];
                #pragma unroll
                for (int j = 0; j < 8; ++j) o[c * 8 + j] += pv * bf2f(vv[j]);
            }
        }
    }
    // store pre-swizzled: granule (c&3) -> (c&3)^((s>>1)&3)  (row mod 128 key)
    size_t rowbase = (((size_t)b * T_ + t) * S_ + s) * (size_t)C_;
    const int key = (s >> 1) & 3;
    #pragma unroll
    for (int c = 0; c < 8; ++c) {
        u16x8 w;
        #pragma unroll
        for (int j = 0; j < 8; ++j) w[j] = f2bf(o[c * 8 + j]);
        int off = h * 64 + (c >> 2) * 32 + (((c & 3) ^ key) << 3);
        *(u16x8*)&attn[rowbase + off] = w;
    }
}

// ---------------------------------------------------------------------------
extern "C" void kernel_launch(void* const* d_in, const int* in_sizes, int n_in,
                              void* d_out, int out_size, void* d_ws, size_t ws_size,
                              hipStream_t stream) {
    const float* x    = (const float*)d_in[0];   // (B, N, C) fp32
    const float* Wqkv = (const float*)d_in[1];   // (512, 1536) fp32
    const float* Wout = (const float*)d_in[2];   // (512, 512) fp32
    float* out = (float*)d_out;

    const size_t xc_elems  = (size_t)M_ * C_;      // 67.1M (x_bf16 / attn, aliased)
    const size_t qkv_elems = (size_t)M_ * 1536;    // 201.3M
    if (ws_size < (xc_elems + qkv_elems) * sizeof(u16)) return;  // 537 MiB

    u16* xb       = (u16*)d_ws;              // [0, 134MB): x_bf16, dead after gemm1
    u16* qkv      = xb + xc_elems;           // [134MB, 537MB)
    u16* attn_buf = xb;                      // alias: written after xb is dead
    u16* WqkvT    = (u16*)d_out;             // scratch in d_out (dead until gemm3)
    u16* WoutT    = qkv;                     // alias: written after qkv is dead

    // 1) weight + activation prep (bf16, pre-swizzled)
    prep_w<<<(1536 * 64) / 256, 256, 0, stream>>>(Wqkv, WqkvT, 1536);
    prep_x<<<8192, 256, 0, stream>>>(x, xb);

    // 2) qkv = x @ W_qkv  (both-sides global_load_lds, bf16 out, linear layout)
    gemm_k<1536, true><<<12288, 256, 0, stream>>>(xb, WqkvT, (void*)qkv, 12);

    // 3) banded temporal attention (reads qkv, writes attn_buf pre-swizzled)
    attn_k<<<B_ * H_ * S_, 64, 0, stream>>>(qkv, attn_buf);

    // 4) WoutT into the now-dead qkv region
    prep_w<<<(512 * 64) / 256, 256, 0, stream>>>(Wout, WoutT, 512);

    // 5) out = attn @ W_out  (both-sides global_load_lds, fp32 out)
    gemm_k<512, false><<<4096, 256, 0, stream>>>(attn_buf, WoutT, (void*)out, 4);
}

// Round 4
// 728.431 us; speedup vs baseline: 1.2120x; 1.0143x over previous
//
#include <hip/hip_runtime.h>
#include <stdint.h>

// Problem constants (fixed instance from setup_inputs)
#define B_   2
#define T_   64
#define S_   1024
#define C_   512
#define H_   8
#define N_   (T_ * S_)      // 65536
#define M_   (B_ * N_)      // 131072
#define WIN_ 5

typedef unsigned short u16;
typedef __bf16 bf16;
typedef __bf16 bf16x8 __attribute__((ext_vector_type(8)));
typedef float  f32x4  __attribute__((ext_vector_type(4)));
typedef u16    u16x8  __attribute__((ext_vector_type(8)));

static __device__ __forceinline__ u16 f2bf(float f) {
    return __builtin_bit_cast(u16, (bf16)f);   // RNE
}
static __device__ __forceinline__ float bf2f(u16 u) {
    return __builtin_bit_cast(float, (uint32_t)u << 16);
}
// async global->LDS, 16B per lane; LDS dest is wave-uniform base + lane*16
static __device__ __forceinline__ void gload16(const void* g, void* l) {
    __builtin_amdgcn_global_load_lds(
        (const __attribute__((address_space(1))) void*)g,
        (__attribute__((address_space(3))) void*)l, 16, 0, 0);
}

// Pre-swizzle layout (applies to every bf16 [row][512] operand):
// logical (row r, chunk c in [0,16), granule g in [0,4), elem j in [0,8))
// stored at r*512 + (c ^ ((r>>3)&1))*32 + ((g ^ ((r>>1)&3))<<3) + j.
// Chunk-XOR spreads BK=64 frag reads across both 64B halves of the 128B LDS
// row; granule-XOR spreads the 4 16B slots -> ds_read_b128 is <=2-way (free).

// ---------------------------------------------------------------------------
// Weight prep: W [512][NCOL] fp32 -> WT [NCOL][512] bf16, pre-swizzled.
// ---------------------------------------------------------------------------
__global__ __launch_bounds__(256) void prep_w(const float* __restrict__ W,
                                              u16* __restrict__ WT, int NCOL) {
    int id = blockIdx.x * 256 + threadIdx.x;
    int n  = id % NCOL;            // consecutive threads -> consecutive n
    int gi = id / NCOL;            // 0..63: granule index within the row
    int chunk = gi >> 2;
    int g     = gi & 3;
    int k0 = chunk * 32 + g * 8;
    int cs = chunk ^ ((n >> 3) & 1);
    int gs = g ^ ((n >> 1) & 3);
    u16x8 w;
    #pragma unroll
    for (int j = 0; j < 8; ++j) w[j] = f2bf(W[(size_t)(k0 + j) * NCOL + n]);
    *(u16x8*)&WT[(size_t)n * 512 + cs * 32 + gs * 8] = w;
}

// ---------------------------------------------------------------------------
// x prep: x [M][512] fp32 -> xb [M][512] bf16, pre-swizzled.
// ---------------------------------------------------------------------------
__global__ __launch_bounds__(256) void prep_x(const float* __restrict__ x,
                                              u16* __restrict__ xb) {
    const size_t total = (size_t)M_ * 64;   // 16B granules
    for (size_t id = (size_t)blockIdx.x * 256 + threadIdx.x; id < total;
         id += (size_t)gridDim.x * 256) {
        size_t r  = id >> 6;
        int   gi  = (int)(id & 63);
        int chunk = gi >> 2;
        int g     = gi & 3;
        int cb    = ((int)r >> 3) & 1;
        int key   = ((int)r >> 1) & 3;
        const float* src = x + r * 512 + chunk * 32 + g * 8;
        u16x8 w;
        #pragma unroll
        for (int j = 0; j < 8; ++j) w[j] = f2bf(src[j]);
        *(u16x8*)&xb[r * 512 + (chunk ^ cb) * 32 + ((g ^ key) << 3)] = w;
    }
}

// ---------------------------------------------------------------------------
// 256x256-tile deep-pipelined GEMM: D[M x NCOL] = A[M x 512] * B[512 x NCOL].
// A [M][512], B(transposed) [NCOL][512], both pre-swizzled bf16.
// 512 threads = 8 waves (2 wm x 4 wn), BK=64, 2 K-tile LDS buffers (128 KiB).
// Schedule per K-tile t: 24 ds_read_b128 -> 32 MFMA(kk0) -> lgkmcnt(0)+bar
//   -> stage tile t+2 (8 global_load_lds) -> 32 MFMA(kk1) -> vmcnt(8)+bar.
// vmcnt never drains to 0 in the main loop (T3+T4); setprio around MFMA (T5).
// ---------------------------------------------------------------------------
template<int NCOL, bool OUT_BF16>
__global__ __launch_bounds__(512, 2) void gemm8_k(const u16* __restrict__ Ap,
                                                  const u16* __restrict__ Bp,
                                                  void* __restrict__ Dp, int gx) {
    __shared__ u16 lds[65536];   // A0 | B0 | A1 | B1, 16384 u16 each

    const int tid  = threadIdx.x;
    const int lane = tid & 63;
    const int wid  = tid >> 6;    // 0..7
    const int wm   = wid >> 2;    // 0..1
    const int wn   = wid & 3;     // 0..3
    const int fr   = lane & 15;
    const int g0   = lane >> 4;

    // XCD-aware bijective swizzle (grid % 8 == 0)
    const int nwg = gridDim.x;
    const int q8  = nwg >> 3;
    const int bid = blockIdx.x;
    const int wg  = (bid & 7) * q8 + (bid >> 3);
    const int bx  = wg % gx;
    const int by  = wg / gx;
    const long row0 = (long)by * 256;
    const int  col0 = bx * 256;

    // per-frag LDS offsets (u16, relative to A/B buffer base), kk=0; kk=1 = ^32
    int aoffs[8], boffs[4];
    #pragma unroll
    for (int mf = 0; mf < 8; ++mf) {
        int lr = wm * 128 + mf * 16 + fr;
        aoffs[mf] = lr * 64 + (((lr >> 3) & 1) << 5) + (((g0 ^ (lr >> 1)) & 3) << 3);
    }
    #pragma unroll
    for (int nf = 0; nf < 4; ++nf) {
        int lc = wn * 64 + nf * 16 + fr;
        boffs[nf] = lc * 64 + (((lc >> 3) & 1) << 5) + (((g0 ^ (lc >> 1)) & 3) << 3);
    }

    const int srow = lane >> 3;        // staging: row within 8-row wave slab
    const int scol = (lane & 7) * 8;   // u16 offset within 128B row window

    f32x4 acc[8][4] = {};

    // stage K-tile t into buffer bb (A: 4 issues, B: 4 issues; 16KB each half)
    auto stage = [&](int t, int bb) {
        const int ab = bb * 32768;
        #pragma unroll
        for (int i = 0; i < 4; ++i) {
            const u16* g = Ap + (row0 + i * 64 + wid * 8 + srow) * 512 + t * 64 + scol;
            gload16(g, (void*)&lds[ab + (i * 64 + wid * 8) * 64]);
        }
        #pragma unroll
        for (int i = 0; i < 4; ++i) {
            const u16* g = Bp + (size_t)(col0 + i * 64 + wid * 8 + srow) * 512 + t * 64 + scol;
            gload16(g, (void*)&lds[ab + 16384 + (i * 64 + wid * 8) * 64]);
        }
    };

    stage(0, 0);
    stage(1, 1);
    asm volatile("s_waitcnt vmcnt(8)" ::: "memory");
    __builtin_amdgcn_sched_barrier(0);
    __builtin_amdgcn_s_barrier();

    #pragma unroll
    for (int t = 0; t < 8; ++t) {
        const int bb = t & 1;
        const int ab = bb * 32768;
        bf16x8 af[2][8], bfv[2][4];
        // ---- 24 ds_read_b128: kk0 set first, then kk1 set ----
        #pragma unroll
        for (int mf = 0; mf < 8; ++mf)
            af[0][mf] = __builtin_bit_cast(bf16x8, *(const u16x8*)&lds[ab + aoffs[mf]]);
        #pragma unroll
        for (int nf = 0; nf < 4; ++nf)
            bfv[0][nf] = __builtin_bit_cast(bf16x8, *(const u16x8*)&lds[ab + 16384 + boffs[nf]]);
        #pragma unroll
        for (int mf = 0; mf < 8; ++mf)
            af[1][mf] = __builtin_bit_cast(bf16x8, *(const u16x8*)&lds[ab + (aoffs[mf] ^ 32)]);
        #pragma unroll
        for (int nf = 0; nf < 4; ++nf)
            bfv[1][nf] = __builtin_bit_cast(bf16x8, *(const u16x8*)&lds[ab + 16384 + (boffs[nf] ^ 32)]);
        // ---- MFMA cluster kk=0 (compiler inserts counted lgkmcnt) ----
        __builtin_amdgcn_s_setprio(1);
        #pragma unroll
        for (int mf = 0; mf < 8; ++mf)
            #pragma unroll
            for (int nf = 0; nf < 4; ++nf)
                acc[mf][nf] = __builtin_amdgcn_mfma_f32_16x16x32_bf16(
                    af[0][mf], bfv[0][nf], acc[mf][nf], 0, 0, 0);
        __builtin_amdgcn_s_setprio(0);
        // ---- all reads of buf[bb] complete -> buffer dead for this wave ----
        asm volatile("s_waitcnt lgkmcnt(0)" ::: "memory");
        __builtin_amdgcn_sched_barrier(0);
        __builtin_amdgcn_s_barrier();
        // ---- prefetch K-tile t+2 into the now-dead buffer ----
        if (t + 2 < 8) stage(t + 2, bb);
        // ---- MFMA cluster kk=1 (register-only) ----
        __builtin_amdgcn_s_setprio(1);
        #pragma unroll
        for (int mf = 0; mf < 8; ++mf)
            #pragma unroll
            for (int nf = 0; nf < 4; ++nf)
                acc[mf][nf] = __builtin_amdgcn_mfma_f32_16x16x32_bf16(
                    af[1][mf], bfv[1][nf], acc[mf][nf], 0, 0, 0);
        __builtin_amdgcn_s_setprio(0);
        // ---- K-tile boundary: tile t+1 must be landed; keep t+2 in flight ----
        if (t <= 5) {
            asm volatile("s_waitcnt vmcnt(8)" ::: "memory");
            __builtin_amdgcn_sched_barrier(0);
            __builtin_amdgcn_s_barrier();
        } else if (t == 6) {
            asm volatile("s_waitcnt vmcnt(0)" ::: "memory");
            __builtin_amdgcn_sched_barrier(0);
            __builtin_amdgcn_s_barrier();
        }
    }

    // ---- epilogue: C row = (lane>>4)*4 + r, col = lane&15 ----
    #pragma unroll
    for (int mf = 0; mf < 8; ++mf) {
        #pragma unroll
        for (int nf = 0; nf < 4; ++nf) {
            #pragma unroll
            for (int r = 0; r < 4; ++r) {
                long grow = row0 + wm * 128 + mf * 16 + (lane >> 4) * 4 + r;
                int  gcol = col0 + wn * 64 + nf * 16 + fr;
                float v = acc[mf][nf][r];
                if constexpr (OUT_BF16) ((u16*)Dp)[grow * NCOL + gcol] = f2bf(v);
                else                    ((float*)Dp)[grow * NCOL + gcol] = v;
            }
        }
    }
}

// ---------------------------------------------------------------------------
// Banded temporal attention. One wave per (b, h, s). qkv layout (linear bf16):
// qkv[((b*T + t)*S + s)*1536 + which*512 + h*64 + d].
// Output rows stored PRE-SWIZZLED (chunk+granule XOR) for gemm3's staging.
// ---------------------------------------------------------------------------
__global__ __launch_bounds__(64) void attn_k(const u16* __restrict__ qkv,
                                             u16* __restrict__ attn) {
    __shared__ u16 Kl[64][72];
    __shared__ u16 Vl[64][72];

    const int tid = threadIdx.x;
    const int bid = blockIdx.x;
    const int s = bid & (S_ - 1);
    const int h = (bid >> 10) & (H_ - 1);
    const int b = bid >> 13;

    const size_t base = ((size_t)b * T_ * S_ + s) * 1536 + h * 64;

    {
        const int rr = tid >> 3;
        const int ch = tid & 7;
        #pragma unroll
        for (int it = 0; it < 8; ++it) {
            int tt = it * 8 + rr;
            size_t off = base + (size_t)tt * (S_ * 1536) + ch * 8;
            *(u16x8*)&Kl[tt][ch * 8] = *(const u16x8*)(qkv + off + 512);
            *(u16x8*)&Vl[tt][ch * 8] = *(const u16x8*)(qkv + off + 1024);
        }
    }
    float qf[64];
    const int t = tid;
    {
        size_t qoff = base + (size_t)t * (S_ * 1536);
        #pragma unroll
        for (int c = 0; c < 8; ++c) {
            u16x8 v = *(const u16x8*)(qkv + qoff + c * 8);
            #pragma unroll
            for (int j = 0; j < 8; ++j) qf[c * 8 + j] = bf2f(v[j]);
        }
    }
    __syncthreads();

    float p[11];
    float m = -1e30f;
    #pragma unroll
    for (int i = 0; i < 11; ++i) {
        int u = t - WIN_ + i;
        if (u >= 0 && u < 64) {
            float dot = 0.f;
            #pragma unroll
            for (int c = 0; c < 8; ++c) {
                u16x8 kv = *(const u16x8*)&Kl[u][c * 8];
                #pragma unroll
                for (int j = 0; j < 8; ++j) dot += qf[c * 8 + j] * bf2f(kv[j]);
            }
            p[i] = dot * 0.125f;
            m = fmaxf(m, p[i]);
        } else {
            p[i] = -1e30f;
        }
    }
    float sum = 0.f;
    #pragma unroll
    for (int i = 0; i < 11; ++i) {
        int u = t - WIN_ + i;
        float e = (u >= 0 && u < 64) ? __expf(p[i] - m) : 0.f;
        p[i] = e;
        sum += e;
    }
    const float inv = 1.f / sum;

    float o[64];
    #pragma unroll
    for (int d = 0; d < 64; ++d) o[d] = 0.f;
    #pragma unroll
    for (int i = 0; i < 11; ++i) {
        int u = t - WIN_ + i;
        if (u >= 0 && u < 64) {
            float pv = p[i] * inv;
            #pragma unroll
            for (int c = 0; c < 8; ++c) {
                u16x8 vv = *(const u16x8*)&Vl[u][c * 8];
                #pragma unroll
                for (int j = 0; j < 8; ++j) o[c * 8 + j] += pv * bf2f(vv[j]);
            }
        }
    }
    // pre-swizzled store: logical chunk 2h+(c>>2), granule c&3, row key from s
    size_t rowbase = (((size_t)b * T_ + t) * S_ + s) * (size_t)C_;
    const int cb  = (s >> 3) & 1;
    const int key = (s >> 1) & 3;
    #pragma unroll
    for (int c = 0; c < 8; ++c) {
        u16x8 w;
        #pragma unroll
        for (int j = 0; j < 8; ++j) w[j] = f2bf(o[c * 8 + j]);
        int off = (((2 * h + (c >> 2)) ^ cb) << 5) + (((c & 3) ^ key) << 3);
        *(u16x8*)&attn[rowbase + off] = w;
    }
}

// ---------------------------------------------------------------------------
extern "C" void kernel_launch(void* const* d_in, const int* in_sizes, int n_in,
                              void* d_out, int out_size, void* d_ws, size_t ws_size,
                              hipStream_t stream) {
    const float* x    = (const float*)d_in[0];   // (B, N, C) fp32
    const float* Wqkv = (const float*)d_in[1];   // (512, 1536) fp32
    const float* Wout = (const float*)d_in[2];   // (512, 512) fp32
    float* out = (float*)d_out;

    const size_t xc_elems  = (size_t)M_ * C_;      // 67.1M (x_bf16 / attn alias)
    const size_t qkv_elems = (size_t)M_ * 1536;    // 201.3M
    if (ws_size < (xc_elems + qkv_elems) * sizeof(u16)) return;  // 537 MiB

    u16* xb       = (u16*)d_ws;              // [0, 134MB): x_bf16, dead after gemm1
    u16* qkv      = xb + xc_elems;           // [134MB, 537MB)
    u16* attn_buf = xb;                      // alias: written after xb is dead
    u16* WqkvT    = (u16*)d_out;             // scratch in d_out (dead until gemm3)
    u16* WoutT    = qkv;                     // alias: written after qkv is dead

    // 1) weight + activation prep (bf16, pre-swizzled)
    prep_w<<<(1536 * 64) / 256, 256, 0, stream>>>(Wqkv, WqkvT, 1536);
    prep_x<<<8192, 256, 0, stream>>>(x, xb);

    // 2) qkv = x @ W_qkv  (256^2 pipelined, bf16 out, linear layout)
    gemm8_k<1536, true><<<3072, 512, 0, stream>>>(xb, WqkvT, (void*)qkv, 6);

    // 3) banded temporal attention (reads qkv, writes attn_buf pre-swizzled)
    attn_k<<<B_ * H_ * S_, 64, 0, stream>>>(qkv, attn_buf);

    // 4) WoutT into the now-dead qkv region
    prep_w<<<(512 * 64) / 256, 256, 0, stream>>>(Wout, WoutT, 512);

    // 5) out = attn @ W_out  (256^2 pipelined, fp32 out)
    gemm8_k<512, false><<<1024, 512, 0, stream>>>(attn_buf, WoutT, (void*)out, 2);
}

// Round 5
// 629.201 us; speedup vs baseline: 1.4032x; 1.1577x over previous
//
#include <hip/hip_runtime.h>
#include <stdint.h>

// Problem constants (fixed instance from setup_inputs)
#define B_   2
#define T_   64
#define S_   1024
#define C_   512
#define H_   8
#define N_   (T_ * S_)      // 65536
#define M_   (B_ * N_)      // 131072
#define WIN_ 5

typedef unsigned short u16;
typedef __bf16 bf16;
typedef __bf16 bf16x8 __attribute__((ext_vector_type(8)));
typedef float  f32x4  __attribute__((ext_vector_type(4)));
typedef u16    u16x8  __attribute__((ext_vector_type(8)));

static __device__ __forceinline__ u16 f2bf(float f) {
    return __builtin_bit_cast(u16, (bf16)f);   // RNE
}
static __device__ __forceinline__ float bf2f(u16 u) {
    return __builtin_bit_cast(float, (uint32_t)u << 16);
}
// async global->LDS, 16B per lane; LDS dest is wave-uniform base + lane*16
static __device__ __forceinline__ void gload16(const void* g, void* l) {
    __builtin_amdgcn_global_load_lds(
        (const __attribute__((address_space(1))) void*)g,
        (__attribute__((address_space(3))) void*)l, 16, 0, 0);
}

// Pre-swizzle layout (applies to every bf16 [row][512] operand):
// logical (row r, chunk c in [0,16), granule g in [0,4), elem j in [0,8))
// stored at r*512 + (c ^ ((r>>3)&1))*32 + ((g ^ ((r>>1)&3))<<3) + j.
// Chunk-XOR spreads BK=64 frag reads across both 64B halves of the 128B LDS
// row; granule-XOR spreads the 4 16B slots -> ds_read_b128 is <=2-way (free,
// measured 0 conflicts in rounds 3-4).

// ---------------------------------------------------------------------------
// Weight prep: W [512][NCOL] fp32 -> WT [NCOL][512] bf16, pre-swizzled.
// ---------------------------------------------------------------------------
__global__ __launch_bounds__(256) void prep_w(const float* __restrict__ W,
                                              u16* __restrict__ WT, int NCOL) {
    int id = blockIdx.x * 256 + threadIdx.x;
    int n  = id % NCOL;
    int gi = id / NCOL;
    int chunk = gi >> 2;
    int g     = gi & 3;
    int k0 = chunk * 32 + g * 8;
    int cs = chunk ^ ((n >> 3) & 1);
    int gs = g ^ ((n >> 1) & 3);
    u16x8 w;
    #pragma unroll
    for (int j = 0; j < 8; ++j) w[j] = f2bf(W[(size_t)(k0 + j) * NCOL + n]);
    *(u16x8*)&WT[(size_t)n * 512 + cs * 32 + gs * 8] = w;
}

// ---------------------------------------------------------------------------
// x prep: x [M][512] fp32 -> xb [M][512] bf16, pre-swizzled.
// ---------------------------------------------------------------------------
__global__ __launch_bounds__(256) void prep_x(const float* __restrict__ x,
                                              u16* __restrict__ xb) {
    const size_t total = (size_t)M_ * 64;   // 16B granules
    for (size_t id = (size_t)blockIdx.x * 256 + threadIdx.x; id < total;
         id += (size_t)gridDim.x * 256) {
        size_t r  = id >> 6;
        int   gi  = (int)(id & 63);
        int chunk = gi >> 2;
        int g     = gi & 3;
        int cb    = ((int)r >> 3) & 1;
        int key   = ((int)r >> 1) & 3;
        const float* src = x + r * 512 + chunk * 32 + g * 8;
        u16x8 w;
        #pragma unroll
        for (int j = 0; j < 8; ++j) w[j] = f2bf(src[j]);
        *(u16x8*)&xb[r * 512 + (chunk ^ cb) * 32 + ((g ^ key) << 3)] = w;
    }
}

#define LDF(off) __builtin_bit_cast(bf16x8, *(const u16x8*)&lds[(off)])
#define MFMA16(d, a, b) d = __builtin_amdgcn_mfma_f32_16x16x32_bf16(a, b, d, 0, 0, 0)

// ---------------------------------------------------------------------------
// 256x256 8-phase pipelined GEMM (m201-style): D[M x NCOL] = A[M x 512] * B.
// A [M][512], B(transposed) [NCOL][512], both pre-swizzled bf16.
// 512 thr = 8 waves (2 wm x 4 wn), BK=64, 2 K-tile dbuf (128 KiB LDS).
// Per K-tile t, 4 phases, each {ds_read subset | stage half-tile | barrier |
// lgkmcnt(0) | 16 MFMA (setprio) | barrier}; vmcnt(4) once per K-tile only.
//   ph0: read A-kk0(8)+B-kk0(4); stage A-lo(t+1); MFMA mf*,nf0-1,kk0
//   ph1: read B-kk1(4);          stage A-hi(t+1); MFMA mf*,nf2-3,kk0
//   ph2: read A-kk1(8);          stage B-lo(t+2); MFMA mf*,nf0-1,kk1
//   ph3: (no reads)              stage B-hi(t+2); MFMA mf*,nf2-3,kk1; vmcnt(4)
// WAR safety: A(t+1) -> other dbuf (freed at t-1/ph2 barrier); B(t+2) -> this
// dbuf's B region (all B reads done by ph1's lgkm+barrier).
// ---------------------------------------------------------------------------
template<int NCOL, bool OUT_BF16>
__global__ __launch_bounds__(512, 2) void gemm8_k(const u16* __restrict__ Ap,
                                                  const u16* __restrict__ Bp,
                                                  void* __restrict__ Dp, int gx) {
    __shared__ u16 lds[65536];   // dbuf0{A,B} | dbuf1{A,B}, 16384 u16 each

    const int tid  = threadIdx.x;
    const int lane = tid & 63;
    const int wid  = tid >> 6;    // 0..7
    const int wm   = wid >> 2;    // 0..1
    const int wn   = wid & 3;     // 0..3
    const int fr   = lane & 15;
    const int g0   = lane >> 4;

    // XCD-aware bijective swizzle (grid % 8 == 0)
    const int nwg = gridDim.x;
    const int q8  = nwg >> 3;
    const int bid = blockIdx.x;
    const int wg  = (bid & 7) * q8 + (bid >> 3);
    const int bx  = wg % gx;
    const int by  = wg / gx;
    const long row0 = (long)by * 256;
    const int  col0 = bx * 256;

    // per-frag LDS offsets (u16, rel. to A/B region base), kk=0; kk=1 = ^32
    int aoffs[8], boffs[4];
    #pragma unroll
    for (int mf = 0; mf < 8; ++mf) {
        int lr = wm * 128 + mf * 16 + fr;
        aoffs[mf] = lr * 64 + (((lr >> 3) & 1) << 5) + (((g0 ^ (lr >> 1)) & 3) << 3);
    }
    #pragma unroll
    for (int nf = 0; nf < 4; ++nf) {
        int lc = wn * 64 + nf * 16 + fr;
        boffs[nf] = lc * 64 + (((lc >> 3) & 1) << 5) + (((g0 ^ (lc >> 1)) & 3) << 3);
    }

    const int srow = lane >> 3;        // staging: row within 8-row wave slab
    const int scol = (lane & 7) * 8;   // u16 offset within 128B row window

    // stage one half-tile (128 rows x 64 k): 2 gload16 per thread
    auto stageA = [&](int tt, int half) {
        const int ab = (tt & 1) * 32768;
        #pragma unroll
        for (int i = 0; i < 2; ++i) {
            int r = half * 128 + i * 64 + wid * 8 + srow;
            const u16* g = Ap + (row0 + r) * 512 + tt * 64 + scol;
            gload16(g, (void*)&lds[ab + r * 64]);
        }
    };
    auto stageB = [&](int tt, int half) {
        const int ab = (tt & 1) * 32768;
        #pragma unroll
        for (int i = 0; i < 2; ++i) {
            int r = half * 128 + i * 64 + wid * 8 + srow;
            const u16* g = Bp + (size_t)(col0 + r) * 512 + tt * 64 + scol;
            gload16(g, (void*)&lds[ab + 16384 + r * 64]);
        }
    };

    f32x4 acc[8][4] = {};

    // ---- prologue: tile0 full + tile1 B (12 loads); keep B(t1) in flight ----
    stageA(0, 0); stageA(0, 1); stageB(0, 0); stageB(0, 1);
    stageB(1, 0); stageB(1, 1);
    asm volatile("s_waitcnt vmcnt(4)" ::: "memory");
    __builtin_amdgcn_sched_barrier(0);
    __builtin_amdgcn_s_barrier();

    #pragma unroll
    for (int t = 0; t < 8; ++t) {
        const int ab = (t & 1) * 32768;
        bf16x8 af0[8], af1[8], bf0[4], bf1[4];
        // ================= phase 0 =================
        #pragma unroll
        for (int mf = 0; mf < 8; ++mf) af0[mf] = LDF(ab + aoffs[mf]);
        #pragma unroll
        for (int nf = 0; nf < 4; ++nf) bf0[nf] = LDF(ab + 16384 + boffs[nf]);
        if (t <= 6) stageA(t + 1, 0);
        __builtin_amdgcn_s_barrier();
        asm volatile("s_waitcnt lgkmcnt(0)" ::: "memory");
        __builtin_amdgcn_sched_barrier(0);
        __builtin_amdgcn_s_setprio(1);
        #pragma unroll
        for (int mf = 0; mf < 8; ++mf) {
            MFMA16(acc[mf][0], af0[mf], bf0[0]);
            MFMA16(acc[mf][1], af0[mf], bf0[1]);
        }
        __builtin_amdgcn_s_setprio(0);
        __builtin_amdgcn_s_barrier();
        // ================= phase 1 =================
        #pragma unroll
        for (int nf = 0; nf < 4; ++nf) bf1[nf] = LDF(ab + 16384 + (boffs[nf] ^ 32));
        if (t <= 6) stageA(t + 1, 1);
        __builtin_amdgcn_s_barrier();
        asm volatile("s_waitcnt lgkmcnt(0)" ::: "memory");
        __builtin_amdgcn_sched_barrier(0);
        __builtin_amdgcn_s_setprio(1);
        #pragma unroll
        for (int mf = 0; mf < 8; ++mf) {
            MFMA16(acc[mf][2], af0[mf], bf0[2]);
            MFMA16(acc[mf][3], af0[mf], bf0[3]);
        }
        __builtin_amdgcn_s_setprio(0);
        __builtin_amdgcn_s_barrier();
        // ================= phase 2 =================
        #pragma unroll
        for (int mf = 0; mf < 8; ++mf) af1[mf] = LDF(ab + (aoffs[mf] ^ 32));
        if (t <= 5) stageB(t + 2, 0);
        __builtin_amdgcn_s_barrier();
        asm volatile("s_waitcnt lgkmcnt(0)" ::: "memory");
        __builtin_amdgcn_sched_barrier(0);
        __builtin_amdgcn_s_setprio(1);
        #pragma unroll
        for (int mf = 0; mf < 8; ++mf) {
            MFMA16(acc[mf][0], af1[mf], bf1[0]);
            MFMA16(acc[mf][1], af1[mf], bf1[1]);
        }
        __builtin_amdgcn_s_setprio(0);
        __builtin_amdgcn_s_barrier();
        // ================= phase 3 =================
        if (t <= 5) stageB(t + 2, 1);
        __builtin_amdgcn_s_barrier();
        __builtin_amdgcn_s_setprio(1);
        #pragma unroll
        for (int mf = 0; mf < 8; ++mf) {
            MFMA16(acc[mf][2], af1[mf], bf1[2]);
            MFMA16(acc[mf][3], af1[mf], bf1[3]);
        }
        __builtin_amdgcn_s_setprio(0);
        if (t <= 5) {
            asm volatile("s_waitcnt vmcnt(4)" ::: "memory");   // t+1 landed, B(t+2) in flight
        } else if (t == 6) {
            asm volatile("s_waitcnt vmcnt(0)" ::: "memory");   // drain before last tile
        }
        __builtin_amdgcn_sched_barrier(0);
        __builtin_amdgcn_s_barrier();
    }

    // ---- epilogue: C row = (lane>>4)*4 + r, col = lane&15 ----
    #pragma unroll
    for (int mf = 0; mf < 8; ++mf) {
        #pragma unroll
        for (int nf = 0; nf < 4; ++nf) {
            #pragma unroll
            for (int r = 0; r < 4; ++r) {
                long grow = row0 + wm * 128 + mf * 16 + (lane >> 4) * 4 + r;
                int  gcol = col0 + wn * 64 + nf * 16 + fr;
                float v = acc[mf][nf][r];
                if constexpr (OUT_BF16) ((u16*)Dp)[grow * NCOL + gcol] = f2bf(v);
                else                    ((float*)Dp)[grow * NCOL + gcol] = v;
            }
        }
    }
}

// ---------------------------------------------------------------------------
// Banded temporal attention. One wave per (b, h, s). qkv layout (linear bf16):
// qkv[((b*T + t)*S + s)*1536 + which*512 + h*64 + d].
// Output rows stored PRE-SWIZZLED (chunk+granule XOR) for gemm3's staging.
// ---------------------------------------------------------------------------
__global__ __launch_bounds__(64) void attn_k(const u16* __restrict__ qkv,
                                             u16* __restrict__ attn) {
    __shared__ u16 Kl[64][72];
    __shared__ u16 Vl[64][72];

    const int tid = threadIdx.x;
    const int bid = blockIdx.x;
    const int s = bid & (S_ - 1);
    const int h = (bid >> 10) & (H_ - 1);
    const int b = bid >> 13;

    const size_t base = ((size_t)b * T_ * S_ + s) * 1536 + h * 64;

    {
        const int rr = tid >> 3;
        const int ch = tid & 7;
        #pragma unroll
        for (int it = 0; it < 8; ++it) {
            int tt = it * 8 + rr;
            size_t off = base + (size_t)tt * (S_ * 1536) + ch * 8;
            *(u16x8*)&Kl[tt][ch * 8] = *(const u16x8*)(qkv + off + 512);
            *(u16x8*)&Vl[tt][ch * 8] = *(const u16x8*)(qkv + off + 1024);
        }
    }
    float qf[64];
    const int t = tid;
    {
        size_t qoff = base + (size_t)t * (S_ * 1536);
        #pragma unroll
        for (int c = 0; c < 8; ++c) {
            u16x8 v = *(const u16x8*)(qkv + qoff + c * 8);
            #pragma unroll
            for (int j = 0; j < 8; ++j) qf[c * 8 + j] = bf2f(v[j]);
        }
    }
    __syncthreads();

    float p[11];
    float m = -1e30f;
    #pragma unroll
    for (int i = 0; i < 11; ++i) {
        int u = t - WIN_ + i;
        if (u >= 0 && u < 64) {
            float dot = 0.f;
            #pragma unroll
            for (int c = 0; c < 8; ++c) {
                u16x8 kv = *(const u16x8*)&Kl[u][c * 8];
                #pragma unroll
                for (int j = 0; j < 8; ++j) dot += qf[c * 8 + j] * bf2f(kv[j]);
            }
            p[i] = dot * 0.125f;
            m = fmaxf(m, p[i]);
        } else {
            p[i] = -1e30f;
        }
    }
    float sum = 0.f;
    #pragma unroll
    for (int i = 0; i < 11; ++i) {
        int u = t - WIN_ + i;
        float e = (u >= 0 && u < 64) ? __expf(p[i] - m) : 0.f;
        p[i] = e;
        sum += e;
    }
    const float inv = 1.f / sum;

    float o[64];
    #pragma unroll
    for (int d = 0; d < 64; ++d) o[d] = 0.f;
    #pragma unroll
    for (int i = 0; i < 11; ++i) {
        int u = t - WIN_ + i;
        if (u >= 0 && u < 64) {
            float pv = p[i] * inv;
            #pragma unroll
            for (int c = 0; c < 8; ++c) {
                u16x8 vv = *(const u16x8*)&Vl[u][c * 8];
                #pragma unroll
                for (int j = 0; j < 8; ++j) o[c * 8 + j] += pv * bf2f(vv[j]);
            }
        }
    }
    // pre-swizzled store: logical chunk 2h+(c>>2), granule c&3, row key from s
    size_t rowbase = (((size_t)b * T_ + t) * S_ + s) * (size_t)C_;
    const int cb  = (s >> 3) & 1;
    const int key = (s >> 1) & 3;
    #pragma unroll
    for (int c = 0; c < 8; ++c) {
        u16x8 w;
        #pragma unroll
        for (int j = 0; j < 8; ++j) w[j] = f2bf(o[c * 8 + j]);
        int off = (((2 * h + (c >> 2)) ^ cb) << 5) + (((c & 3) ^ key) << 3);
        *(u16x8*)&attn[rowbase + off] = w;
    }
}

// ---------------------------------------------------------------------------
extern "C" void kernel_launch(void* const* d_in, const int* in_sizes, int n_in,
                              void* d_out, int out_size, void* d_ws, size_t ws_size,
                              hipStream_t stream) {
    const float* x    = (const float*)d_in[0];   // (B, N, C) fp32
    const float* Wqkv = (const float*)d_in[1];   // (512, 1536) fp32
    const float* Wout = (const float*)d_in[2];   // (512, 512) fp32
    float* out = (float*)d_out;

    const size_t xc_elems  = (size_t)M_ * C_;      // 67.1M (x_bf16 / attn alias)
    const size_t qkv_elems = (size_t)M_ * 1536;    // 201.3M
    if (ws_size < (xc_elems + qkv_elems) * sizeof(u16)) return;  // 537 MiB

    u16* xb       = (u16*)d_ws;              // [0, 134MB): x_bf16, dead after gemm1
    u16* qkv      = xb + xc_elems;           // [134MB, 537MB)
    u16* attn_buf = xb;                      // alias: written after xb is dead
    u16* WqkvT    = (u16*)d_out;             // scratch in d_out (dead until gemm3)
    u16* WoutT    = qkv;                     // alias: written after qkv is dead

    // 1) weight + activation prep (bf16, pre-swizzled)
    prep_w<<<(1536 * 64) / 256, 256, 0, stream>>>(Wqkv, WqkvT, 1536);
    prep_x<<<8192, 256, 0, stream>>>(x, xb);

    // 2) qkv = x @ W_qkv  (256^2 8-phase, bf16 out, linear layout)
    gemm8_k<1536, true><<<3072, 512, 0, stream>>>(xb, WqkvT, (void*)qkv, 6);

    // 3) banded temporal attention (reads qkv, writes attn_buf pre-swizzled)
    attn_k<<<B_ * H_ * S_, 64, 0, stream>>>(qkv, attn_buf);

    // 4) WoutT into the now-dead qkv region
    prep_w<<<(512 * 64) / 256, 256, 0, stream>>>(Wout, WoutT, 512);

    // 5) out = attn @ W_out  (256^2 8-phase, fp32 out)
    gemm8_k<512, false><<<1024, 512, 0, stream>>>(attn_buf, WoutT, (void*)out, 2);
}